// Round 1
// baseline (918.072 us; speedup 1.0000x reference)
//
#include <hip/hip_runtime.h>
#include <math.h>

#define NPOS 110592          // 48*48*48
#define NBLK 432             // NPOS / 256

// ---------------- Pass 1: rmsnorm + k,v conv + global exp(k)*v / exp(k) reduction ----------------
__global__ __launch_bounds__(256) void la_pass1(
    const float* __restrict__ x, const float* __restrict__ g_in,
    const float* __restrict__ w_qkv, float* __restrict__ ctxS, float* __restrict__ zS)
{
    __shared__ float eks[32 * 257];
    __shared__ float vvs[32 * 257];

    const int tid   = threadIdx.x;
    const int batch = blockIdx.x / NBLK;
    const int chunk = blockIdx.x % NBLK;
    const int pos   = chunk * 256 + tid;
    const float* xb = x + (size_t)batch * 64 * NPOS;

    // load x[:,pos], rmsnorm over channels (c=64, norm * sqrt(64))
    float xn[64];
    float sumsq = 0.f;
#pragma unroll
    for (int c = 0; c < 64; ++c) {
        float t = xb[(size_t)c * NPOS + pos];
        xn[c] = t;
        sumsq += t * t;
    }
    float rn = 8.0f / fmaxf(sqrtf(sumsq), 1e-12f);
#pragma unroll
    for (int c = 0; c < 64; ++c) xn[c] *= rn * g_in[c];

    const int dg = tid & 15, eg = tid >> 4;
    const int d0 = dg * 2, e0 = eg * 2;
    float acc[4][4];
    float zacc[4][2];

    for (int h = 0; h < 4; ++h) {
        // ---- stage A: k,v for my position (weights are lane-uniform -> scalar loads) ----
        for (int d = 0; d < 32; ++d) {
            const float* wr = w_qkv + (size_t)(128 + h * 32 + d) * 64;
            float a = 0.f;
#pragma unroll
            for (int c = 0; c < 64; ++c) a += wr[c] * xn[c];
            eks[d * 257 + tid] = __expf(a);   // softmax shift-invariant; |k| small -> no max pass
        }
        for (int e = 0; e < 32; ++e) {
            const float* wr = w_qkv + (size_t)(256 + h * 32 + e) * 64;
            float a = 0.f;
#pragma unroll
            for (int c = 0; c < 64; ++c) a += wr[c] * xn[c];
            vvs[e * 257 + tid] = a;
        }
        __syncthreads();

        // ---- stage B: block-local ctx[d,e] += ek[d,p]*v[e,p], each thread owns 2x2 ----
        float a0 = 0.f, a1 = 0.f, a2 = 0.f, a3 = 0.f, z0 = 0.f, z1 = 0.f;
#pragma unroll 4
        for (int p = 0; p < 256; ++p) {
            float k0 = eks[d0 * 257 + p];
            float k1 = eks[(d0 + 1) * 257 + p];
            float v0 = vvs[e0 * 257 + p];
            float v1 = vvs[(e0 + 1) * 257 + p];
            a0 += k0 * v0; a1 += k0 * v1; a2 += k1 * v0; a3 += k1 * v1;
            z0 += k0; z1 += k1;
        }
        acc[h][0] = a0; acc[h][1] = a1; acc[h][2] = a2; acc[h][3] = a3;
        zacc[h][0] = z0; zacc[h][1] = z1;
        __syncthreads();
    }

    float* cb = ctxS + (size_t)batch * 4096;
    float* zb = zS + batch * 128;
#pragma unroll
    for (int h = 0; h < 4; ++h) {
        atomicAdd(&cb[h * 1024 + d0 * 32 + e0],           acc[h][0]);
        atomicAdd(&cb[h * 1024 + d0 * 32 + e0 + 1],       acc[h][1]);
        atomicAdd(&cb[h * 1024 + (d0 + 1) * 32 + e0],     acc[h][2]);
        atomicAdd(&cb[h * 1024 + (d0 + 1) * 32 + e0 + 1], acc[h][3]);
        if (eg == 0) {
            atomicAdd(&zb[h * 32 + d0],     zacc[h][0]);
            atomicAdd(&zb[h * 32 + d0 + 1], zacc[h][1]);
        }
    }
}

// ---------------- Kernel 2: fold in mem_kv, normalize by Z ----------------
__global__ __launch_bounds__(256) void la_finalize(
    const float* __restrict__ ctxS, const float* __restrict__ zS,
    const float* __restrict__ mem_kv, float* __restrict__ ctxF)
{
    int i = blockIdx.x * 256 + threadIdx.x;   // 0..8191
    int b = i >> 12;
    int r = i & 4095;
    int h = r >> 10;
    int de = r & 1023;
    int d = de >> 5, e = de & 31;

    const float* mk = mem_kv + h * 128 + d * 4;        // mem_kv[0][h][d][m]
    const float* mv = mem_kv + 512 + h * 128 + e * 4;  // mem_kv[1][h][e][m]
    float S = ctxS[i];
    float Z = zS[b * 128 + h * 32 + d];
#pragma unroll
    for (int m = 0; m < 4; ++m) {
        float ek = __expf(mk[m]);
        S += ek * mv[m];
        Z += ek;
    }
    ctxF[i] = S / Z;
}

// ---------------- Pass 2: q conv + local softmax + ctx apply + w_out + rmsnorm ----------------
__global__ __launch_bounds__(256) void la_pass2(
    const float* __restrict__ x, const float* __restrict__ g_in,
    const float* __restrict__ w_qkv, const float* __restrict__ ctxF,
    const float* __restrict__ w_out, const float* __restrict__ b_out,
    const float* __restrict__ g_out, float* __restrict__ out)
{
    const int tid   = threadIdx.x;
    const int batch = blockIdx.x / NBLK;
    const int pos   = (blockIdx.x % NBLK) * 256 + tid;
    const float* xb = x + (size_t)batch * 64 * NPOS;

    float xn[64];
    float sumsq = 0.f;
#pragma unroll
    for (int c = 0; c < 64; ++c) {
        float t = xb[(size_t)c * NPOS + pos];
        xn[c] = t;
        sumsq += t * t;
    }
    float rn = 8.0f / fmaxf(sqrtf(sumsq), 1e-12f);
#pragma unroll
    for (int c = 0; c < 64; ++c) xn[c] *= rn * g_in[c];

    const float scale = 0.17677669529663687f;  // 32^-0.5
    float outc[64];
#pragma unroll
    for (int c = 0; c < 64; ++c) outc[c] = b_out[c];

    const float* cb = ctxF + (size_t)batch * 4096;

    for (int h = 0; h < 4; ++h) {
        // q softmax over d without max-subtraction (|q| small, shift-invariant),
        // fused so no runtime-indexed register array exists.
        float hid[32];
#pragma unroll
        for (int e = 0; e < 32; ++e) hid[e] = 0.f;
        float s = 0.f;
        for (int d = 0; d < 32; ++d) {
            const float* wr = w_qkv + (size_t)(h * 32 + d) * 64;
            float a = 0.f;
#pragma unroll
            for (int c = 0; c < 64; ++c) a += wr[c] * xn[c];
            float ed = __expf(a);
            s += ed;
            const float* cr = cb + h * 1024 + d * 32;   // lane-uniform -> scalar loads
#pragma unroll
            for (int e = 0; e < 32; ++e) hid[e] += ed * cr[e];
        }
        float inv = scale / s;
#pragma unroll
        for (int e = 0; e < 32; ++e) hid[e] *= inv;

        // outc[c] += w_out[c, h*32 + e] * hid[e]
#pragma unroll
        for (int c = 0; c < 64; ++c) {
            float a = outc[c];
            const float* wr = w_out + c * 128 + h * 32;
#pragma unroll
            for (int e = 0; e < 32; ++e) a += wr[e] * hid[e];
            outc[c] = a;
        }
    }

    float s2 = 0.f;
#pragma unroll
    for (int c = 0; c < 64; ++c) s2 += outc[c] * outc[c];
    float rn2 = 8.0f / fmaxf(sqrtf(s2), 1e-12f);

    float* ob = out + (size_t)batch * 64 * NPOS;
#pragma unroll
    for (int c = 0; c < 64; ++c)
        ob[(size_t)c * NPOS + pos] = outc[c] * rn2 * g_out[c];
}

extern "C" void kernel_launch(void* const* d_in, const int* in_sizes, int n_in,
                              void* d_out, int out_size, void* d_ws, size_t ws_size,
                              hipStream_t stream) {
    const float* x      = (const float*)d_in[0];
    const float* g_in   = (const float*)d_in[1];
    const float* w_qkv  = (const float*)d_in[2];
    const float* mem_kv = (const float*)d_in[3];
    const float* w_out  = (const float*)d_in[4];
    const float* b_out  = (const float*)d_in[5];
    const float* g_out  = (const float*)d_in[6];
    float* out = (float*)d_out;

    float* ctxS = (float*)d_ws;          // 2*4096
    float* zS   = ctxS + 8192;           // 2*128
    float* ctxF = ctxS + 8448;           // 2*4096

    hipMemsetAsync(d_ws, 0, 8448 * sizeof(float), stream);
    la_pass1<<<2 * NBLK, 256, 0, stream>>>(x, g_in, w_qkv, ctxS, zS);
    la_finalize<<<32, 256, 0, stream>>>(ctxS, zS, mem_kv, ctxF);
    la_pass2<<<2 * NBLK, 256, 0, stream>>>(x, g_in, w_qkv, ctxF, w_out, b_out, g_out, out);
}

// Round 2
// 216.839 us; speedup vs baseline: 4.2339x; 4.2339x over previous
//
#include <hip/hip_runtime.h>
#include <math.h>

#define NPOS 110592
#define NBLK 432

typedef float f32x4 __attribute__((ext_vector_type(4)));
typedef short bf16x8 __attribute__((ext_vector_type(8)));
typedef int   i32x4 __attribute__((ext_vector_type(4)));

#define MFMA __builtin_amdgcn_mfma_f32_16x16x32_bf16

__device__ __forceinline__ short f2bf(float f) {
    unsigned u = __builtin_bit_cast(unsigned, f);
    u += 0x7fffu + ((u >> 16) & 1u);
    return (short)(u >> 16);
}
__device__ __forceinline__ unsigned pack2(float a, float b) {
    return (unsigned)(unsigned short)f2bf(a) | ((unsigned)(unsigned short)f2bf(b) << 16);
}

// ---- shared phase A/B: rmsnorm -> Xn LDS ([256][72] bf16, stride 144B) -> cache A-frags ----
__device__ __forceinline__ void load_frags(const float* __restrict__ x,
                                           const float* __restrict__ g_in,
                                           int batch, int posbase, int tid,
                                           char* smem, bf16x8 af[4][2])
{
    const int lane = tid & 63, wid = tid >> 6, g = (lane >> 4), m15 = lane & 15;
    const int pos = posbase + tid;
    const float* xb = x + (size_t)batch * 64 * NPOS + pos;
    float xn[64]; float ss = 0.f;
#pragma unroll
    for (int c = 0; c < 64; ++c) { float t = xb[(size_t)c * NPOS]; xn[c] = t; ss += t * t; }
    float rn = 8.0f / fmaxf(sqrtf(ss), 1e-12f);
#pragma unroll
    for (int c = 0; c < 64; ++c) xn[c] *= rn * g_in[c];
    char* xrow = smem + tid * 144;
#pragma unroll
    for (int ch = 0; ch < 8; ++ch) {
        i32x4 w;
        w.x = (int)pack2(xn[ch * 8 + 0], xn[ch * 8 + 1]);
        w.y = (int)pack2(xn[ch * 8 + 2], xn[ch * 8 + 3]);
        w.z = (int)pack2(xn[ch * 8 + 4], xn[ch * 8 + 5]);
        w.w = (int)pack2(xn[ch * 8 + 6], xn[ch * 8 + 7]);
        *(i32x4*)(xrow + ch * 16) = w;
    }
    __syncthreads();
    const int strip = wid * 64;
#pragma unroll
    for (int mt = 0; mt < 4; ++mt)
#pragma unroll
        for (int kf = 0; kf < 2; ++kf) {
            int row = strip + mt * 16 + m15;
            af[mt][kf] = *(const bf16x8*)(smem + row * 144 + kf * 64 + g * 16);
        }
    __syncthreads();   // Xn region free after this
}

// ---- prep: fp32 weights -> bf16 copies in ws ----
__global__ __launch_bounds__(256) void la_prep(const float* __restrict__ wqkv,
                                               const float* __restrict__ wout,
                                               short* __restrict__ wqkv_bf,
                                               short* __restrict__ wout_bf)
{
    int i = blockIdx.x * 256 + threadIdx.x;
    if (i < 24576) wqkv_bf[i] = f2bf(wqkv[i]);
    if (i < 8192)  wout_bf[i]  = f2bf(wout[i]);
}

// ---- pass1: Xn -> K,V GEMM -> exp -> EKT/VT (transposed LDS) -> ctx outer-product GEMM ----
__global__ __launch_bounds__(256) void la_pass1(
    const float* __restrict__ x, const float* __restrict__ g_in,
    const short* __restrict__ wkv, float* __restrict__ ctxS, float* __restrict__ zS)
{
    __shared__ char smem[131072];
    const int tid = threadIdx.x;
    const int lane = tid & 63, wid = tid >> 6, g = lane >> 4, m15 = lane & 15;
    const int batch = blockIdx.x / NBLK;
    const int posbase = (blockIdx.x % NBLK) * 256;
    bf16x8 af[4][2];
    load_frags(x, g_in, batch, posbase, tid, smem, af);
    const int strip = wid * 64;

    // EKT: smem[0..64K)  [128 d][256 p] bf16, stride 512B, 16B-chunk XOR swizzle
    // VT : smem[64K..128K) same shape for e rows
    for (int nt = 0; nt < 16; ++nt) {
        int n = nt * 16 + m15;
        const short* wr = wkv + (size_t)(128 + n) * 64 + g * 8;
        bf16x8 b0 = *(const bf16x8*)wr;
        bf16x8 b1 = *(const bf16x8*)(wr + 32);
        float zacc = 0.f;
#pragma unroll
        for (int mt = 0; mt < 4; ++mt) {
            f32x4 acc = {0.f, 0.f, 0.f, 0.f};
            acc = MFMA(af[mt][0], b0, acc, 0, 0, 0);
            acc = MFMA(af[mt][1], b1, acc, 0, 0, 0);
            int prow = strip + mt * 16 + g * 4;
            int chunk = prow >> 3;
            int sub = (prow & 7) * 2;
            if (nt < 8) {
                float e0 = __expf(acc[0]), e1 = __expf(acc[1]);
                float e2 = __expf(acc[2]), e3 = __expf(acc[3]);
                zacc += (e0 + e1) + (e2 + e3);
                int d = nt * 16 + m15;
                char* dst = smem + d * 512 + ((chunk ^ (d & 7)) << 4) + sub;
                *(unsigned long long*)dst =
                    (unsigned long long)pack2(e0, e1) | ((unsigned long long)pack2(e2, e3) << 32);
            } else {
                int e = (nt - 8) * 16 + m15;
                char* dst = smem + 65536 + e * 512 + ((chunk ^ (e & 7)) << 4) + sub;
                *(unsigned long long*)dst =
                    (unsigned long long)pack2(acc[0], acc[1]) | ((unsigned long long)pack2(acc[2], acc[3]) << 32);
            }
        }
        if (nt < 8) {
            zacc += __shfl_xor(zacc, 16);
            zacc += __shfl_xor(zacc, 32);
            if (g == 0) atomicAdd(&zS[batch * 128 + nt * 16 + m15], zacc);
        }
    }
    __syncthreads();

    // ctx GEMM: wave = head; D[d][e] = sum_p EKT[d][p]*VT[e][p], K=256
    {
        const int h = wid;
        f32x4 acc[2][2];
#pragma unroll
        for (int a2 = 0; a2 < 2; ++a2)
#pragma unroll
            for (int b2 = 0; b2 < 2; ++b2) acc[a2][b2] = (f32x4){0.f, 0.f, 0.f, 0.f};
#pragma unroll
        for (int kf = 0; kf < 8; ++kf) {
            int cb16 = kf * 4 + g;
            int r0 = h * 32 + m15, r1 = r0 + 16;
            bf16x8 a0 = *(const bf16x8*)(smem + r0 * 512 + ((cb16 ^ (r0 & 7)) << 4));
            bf16x8 a1 = *(const bf16x8*)(smem + r1 * 512 + ((cb16 ^ (r1 & 7)) << 4));
            bf16x8 v0 = *(const bf16x8*)(smem + 65536 + r0 * 512 + ((cb16 ^ (r0 & 7)) << 4));
            bf16x8 v1 = *(const bf16x8*)(smem + 65536 + r1 * 512 + ((cb16 ^ (r1 & 7)) << 4));
            acc[0][0] = MFMA(a0, v0, acc[0][0], 0, 0, 0);
            acc[0][1] = MFMA(a0, v1, acc[0][1], 0, 0, 0);
            acc[1][0] = MFMA(a1, v0, acc[1][0], 0, 0, 0);
            acc[1][1] = MFMA(a1, v1, acc[1][1], 0, 0, 0);
        }
        float* cbase = ctxS + ((size_t)batch * 4 + h) * 1024;
#pragma unroll
        for (int mt = 0; mt < 2; ++mt)
#pragma unroll
            for (int ntt = 0; ntt < 2; ++ntt)
#pragma unroll
                for (int r = 0; r < 4; ++r) {
                    int d = mt * 16 + g * 4 + r;
                    int e = ntt * 16 + m15;
                    atomicAdd(&cbase[d * 32 + e], acc[mt][ntt][r]);
                }
    }
}

// ---- finalize: fold mem_kv, divide by Z, write ctxT[b][h][48][32] bf16 (d contiguous) ----
__global__ __launch_bounds__(256) void la_finalize(
    const float* __restrict__ ctxS, const float* __restrict__ zS,
    const float* __restrict__ mem_kv, short* __restrict__ ctxT)
{
    int i = blockIdx.x * 256 + threadIdx.x;   // 2*4*48*32 = 12288
    if (i >= 12288) return;
    int b = i / 6144;
    int r = i % 6144;
    int h = r / 1536;
    int r2 = r % 1536;
    int ep = r2 / 32;
    int d = r2 & 31;
    float val;
    if (ep < 32) {
        float S = ctxS[((size_t)(b * 4 + h) * 32 + d) * 32 + ep];
        float Z = zS[b * 128 + h * 32 + d];
        const float* mk = mem_kv + (h * 32 + d) * 4;
        const float* mv = mem_kv + 512 + (h * 32 + ep) * 4;
#pragma unroll
        for (int m = 0; m < 4; ++m) {
            float ek = __expf(mk[m]);
            S += ek * mv[m];
            Z += ek;
        }
        val = S / Z;
    } else if (ep == 32) val = 1.0f;
    else val = 0.0f;
    ctxT[((b * 4 + h) * 48 + ep) * 32 + d] = f2bf(val);
}

// ---- pass2: Xn -> Q GEMM -> exp -> hid GEMM (denominator = ones column) -> Wout GEMM -> rmsnorm ----
__global__ __launch_bounds__(256) void la_pass2(
    const float* __restrict__ x, const float* __restrict__ g_in,
    const short* __restrict__ wq, const short* __restrict__ ctxT,
    const short* __restrict__ wout, const float* __restrict__ b_out,
    const float* __restrict__ g_out, float* __restrict__ out)
{
    __shared__ char smem[131072];
    const int tid = threadIdx.x;
    const int lane = tid & 63, wid = tid >> 6, g = lane >> 4, m15 = lane & 15;
    const int batch = blockIdx.x / NBLK;
    const int posbase = (blockIdx.x % NBLK) * 256;
    bf16x8 af[4][2];
    load_frags(x, g_in, batch, posbase, tid, smem, af);
    const int strip = wid * 64;
    char* EQ = smem;            // [256][128] bf16, stride 256B, chunk-swizzled
    char* HID = smem + 65536;   // same shape

    // GEMM1: EQ = exp(Xn * Wq^T)
    for (int nt = 0; nt < 8; ++nt) {
        int n = nt * 16 + m15;
        const short* wr = wq + (size_t)n * 64 + g * 8;
        bf16x8 b0 = *(const bf16x8*)wr;
        bf16x8 b1 = *(const bf16x8*)(wr + 32);
#pragma unroll
        for (int mt = 0; mt < 4; ++mt) {
            f32x4 acc = {0.f, 0.f, 0.f, 0.f};
            acc = MFMA(af[mt][0], b0, acc, 0, 0, 0);
            acc = MFMA(af[mt][1], b1, acc, 0, 0, 0);
            int cbyte = n * 2;
            int chunk = cbyte >> 4, sub = cbyte & 15;
#pragma unroll
            for (int r = 0; r < 4; ++r) {
                int row = strip + mt * 16 + g * 4 + r;
                *(short*)(EQ + row * 256 + ((chunk ^ (row & 7)) << 4) + sub) = f2bf(__expf(acc[r]));
            }
        }
    }
    __syncthreads();

    // GEMM2: HID = (EQ * ctxT) * scale / denom  (denom = ones column, col 32 of 48)
    const short* ctb = ctxT + batch * 4 * 48 * 32;
    const float scale = 0.17677669529663687f;
#pragma unroll
    for (int h = 0; h < 4; ++h) {
        bf16x8 c0 = *(const bf16x8*)(ctb + (h * 48 + m15) * 32 + g * 8);
        bf16x8 c1 = *(const bf16x8*)(ctb + (h * 48 + 16 + m15) * 32 + g * 8);
        bf16x8 c2 = *(const bf16x8*)(ctb + (h * 48 + 32 + m15) * 32 + g * 8);
#pragma unroll
        for (int mt = 0; mt < 4; ++mt) {
            int rowa = strip + mt * 16 + m15;
            int ch = (h * 4 + g) ^ (rowa & 7);
            bf16x8 a = *(const bf16x8*)(EQ + rowa * 256 + (ch << 4));
            f32x4 p0 = {0.f,0.f,0.f,0.f}, p1 = {0.f,0.f,0.f,0.f}, p2 = {0.f,0.f,0.f,0.f};
            p0 = MFMA(a, c0, p0, 0, 0, 0);
            p1 = MFMA(a, c1, p1, 0, 0, 0);
            p2 = MFMA(a, c2, p2, 0, 0, 0);
#pragma unroll
            for (int r = 0; r < 4; ++r) {
                float dn = __shfl(p2[r], lane & 48);
                float inv = scale / dn;
                int row = strip + mt * 16 + g * 4 + r;
                int ca = (h * 32 + m15) * 2;
                *(short*)(HID + row * 256 + (((ca >> 4) ^ (row & 7)) << 4) + (ca & 15)) = f2bf(p0[r] * inv);
                int cb2 = (h * 32 + 16 + m15) * 2;
                *(short*)(HID + row * 256 + (((cb2 >> 4) ^ (row & 7)) << 4) + (cb2 & 15)) = f2bf(p1[r] * inv);
            }
        }
    }
    __syncthreads();

    // GEMM3: OUT = HID * Wout^T + b_out, then rmsnorm*g_out -> staged transposed in smem[0..64K)
    bf16x8 wb[4][4];
#pragma unroll
    for (int nt = 0; nt < 4; ++nt)
#pragma unroll
        for (int kf = 0; kf < 4; ++kf)
            wb[nt][kf] = *(const bf16x8*)(wout + (size_t)(nt * 16 + m15) * 128 + kf * 32 + g * 8);
    float bo[4], go[4];
#pragma unroll
    for (int nt = 0; nt < 4; ++nt) { bo[nt] = b_out[nt * 16 + m15]; go[nt] = g_out[nt * 16 + m15]; }

#pragma unroll
    for (int mt = 0; mt < 4; ++mt) {
        int rowa = strip + mt * 16 + m15;
        bf16x8 a[4];
#pragma unroll
        for (int kf = 0; kf < 4; ++kf) {
            int ch = (kf * 4 + g) ^ (rowa & 7);
            a[kf] = *(const bf16x8*)(HID + rowa * 256 + (ch << 4));
        }
        f32x4 acc[4];
#pragma unroll
        for (int nt = 0; nt < 4; ++nt) acc[nt] = (f32x4){0.f, 0.f, 0.f, 0.f};
#pragma unroll
        for (int nt = 0; nt < 4; ++nt)
#pragma unroll
            for (int kf = 0; kf < 4; ++kf)
                acc[nt] = MFMA(a[kf], wb[nt][kf], acc[nt], 0, 0, 0);
#pragma unroll
        for (int r = 0; r < 4; ++r) {
            float v0 = acc[0][r] + bo[0], v1 = acc[1][r] + bo[1];
            float v2 = acc[2][r] + bo[2], v3 = acc[3][r] + bo[3];
            float s = v0 * v0 + v1 * v1 + v2 * v2 + v3 * v3;
            s += __shfl_xor(s, 1); s += __shfl_xor(s, 2);
            s += __shfl_xor(s, 4); s += __shfl_xor(s, 8);
            float rn2 = 8.0f / fmaxf(sqrtf(s), 1e-12f);
            int posl = strip + mt * 16 + g * 4 + r;
            int chunkbase = posl >> 2;
            float vv[4] = {v0, v1, v2, v3};
#pragma unroll
            for (int nt = 0; nt < 4; ++nt) {
                int c = nt * 16 + m15;
                *(float*)(smem + c * 1024 + ((chunkbase ^ (c & 15)) << 4) + (posl & 3) * 4) =
                    vv[nt] * rn2 * go[nt];
            }
        }
    }
    __syncthreads();
    // coalesced store: [64 c][256 pos] fp32, chunk-swizzled
    float* ob = out + (size_t)batch * 64 * NPOS + posbase;
    int pq = tid & 63, cb4 = tid >> 6;
#pragma unroll
    for (int i = 0; i < 16; ++i) {
        int c = i * 4 + cb4;
        f32x4 v = *(const f32x4*)(smem + c * 1024 + ((pq ^ (c & 15)) << 4));
        *(f32x4*)(ob + (size_t)c * NPOS + pq * 4) = v;
    }
}

extern "C" void kernel_launch(void* const* d_in, const int* in_sizes, int n_in,
                              void* d_out, int out_size, void* d_ws, size_t ws_size,
                              hipStream_t stream) {
    const float* x      = (const float*)d_in[0];
    const float* g_in   = (const float*)d_in[1];
    const float* w_qkv  = (const float*)d_in[2];
    const float* mem_kv = (const float*)d_in[3];
    const float* w_out  = (const float*)d_in[4];
    const float* b_out  = (const float*)d_in[5];
    const float* g_out  = (const float*)d_in[6];
    float* out = (float*)d_out;

    char* ws = (char*)d_ws;
    float* ctxS    = (float*)ws;             // 8192 f32
    float* zS      = (float*)(ws + 32768);   // 256 f32
    short* wqkv_bf = (short*)(ws + 33792);   // 24576 bf16
    short* wout_bf = (short*)(ws + 82944);   // 8192 bf16
    short* ctxT    = (short*)(ws + 99328);   // 12288 bf16

    hipMemsetAsync(d_ws, 0, 33792, stream);
    la_prep<<<96, 256, 0, stream>>>(w_qkv, w_out, wqkv_bf, wout_bf);
    la_pass1<<<2 * NBLK, 256, 0, stream>>>(x, g_in, wqkv_bf, ctxS, zS);
    la_finalize<<<48, 256, 0, stream>>>(ctxS, zS, mem_kv, ctxT);
    la_pass2<<<2 * NBLK, 256, 0, stream>>>(x, g_in, wqkv_bf, ctxT, wout_bf, b_out, g_out, out);
}